// Round 5
// baseline (278.078 us; speedup 1.0000x reference)
//
#include <hip/hip_runtime.h>
#include <hip/hip_bf16.h>

// Decoder block, round 5: GEMM re-geometried to the LDS-BW-optimal point:
// BM=BN=256, BK=32, 8 waves, wave tile 128x64 (mfma_32x32x16), 4 LDS K-tile
// buffers with distance-2 prefetch, counted vmcnt(4), raw s_barrier, T2
// swizzle (64B rows), T5 setprio. Attention/LN/prep unchanged from round 4.

#define D_MODEL 512
#define N_HEADS 8
#define D_HEAD 64
#define D_FF 2048
#define NROWS 16384   // B*T

typedef __bf16 bf16x8 __attribute__((ext_vector_type(8)));
typedef float f32x4 __attribute__((ext_vector_type(4)));
typedef float f32x16 __attribute__((ext_vector_type(16)));

// XOR swizzle within a 128B-row tile: involution, bits 4-6 ^= row&7 (attn).
#define SWZ(x) ((x) ^ ((((x) >> 7) & 7) << 4))

static __device__ __forceinline__ ushort f2bf(float f) {
    union { float f; unsigned u; } v; v.f = f;
    unsigned r = v.u + 0x7fffu + ((v.u >> 16) & 1u);   // RNE
    return (ushort)(r >> 16);
}
static __device__ __forceinline__ unsigned pack2(float lo, float hi) {
    return (unsigned)f2bf(lo) | ((unsigned)f2bf(hi) << 16);
}
static __device__ __forceinline__ void async16(const void* g, void* l) {
    __builtin_amdgcn_global_load_lds(
        (const __attribute__((address_space(1))) void*)g,
        (__attribute__((address_space(3))) void*)l, 16, 0, 0);
}

// ---------------------------------------------------------------- fp32 -> bf16
__global__ __launch_bounds__(256) void conv_bf_kernel(
    const float* __restrict__ src, ushort* __restrict__ dst, int n8)
{
    int i = blockIdx.x * 256 + threadIdx.x;
    if (i >= n8) return;
    const float4* s = (const float4*)src;
    float4 a = s[i * 2], b = s[i * 2 + 1];
    uint4 o;
    o.x = pack2(a.x, a.y); o.y = pack2(a.z, a.w);
    o.z = pack2(b.x, b.y); o.w = pack2(b.z, b.w);
    ((uint4*)dst)[i] = o;
}

// ---------------------------------------------------------------- transpose fp32[R][C] -> bf16[C][R]
static __device__ __forceinline__ void tile_transpose_body(
    const float* __restrict__ src, int srcldc, ushort* __restrict__ dst, int Rd,
    int r0, int c0)
{
    __shared__ float t[64][65];
    int tid = threadIdx.x;
    int lr = tid >> 4, lc4 = (tid & 15) * 4;
    #pragma unroll
    for (int i = 0; i < 4; ++i) {
        float4 v = *(const float4*)&src[(size_t)(r0 + lr + i * 16) * srcldc + c0 + lc4];
        t[lr + i * 16][lc4 + 0] = v.x;
        t[lr + i * 16][lc4 + 1] = v.y;
        t[lr + i * 16][lc4 + 2] = v.z;
        t[lr + i * 16][lc4 + 3] = v.w;
    }
    __syncthreads();
    int oc = tid >> 2, orr = (tid & 3) * 16;
    uint4 u0, u1;
    u0.x = pack2(t[orr + 0][oc],  t[orr + 1][oc]);
    u0.y = pack2(t[orr + 2][oc],  t[orr + 3][oc]);
    u0.z = pack2(t[orr + 4][oc],  t[orr + 5][oc]);
    u0.w = pack2(t[orr + 6][oc],  t[orr + 7][oc]);
    u1.x = pack2(t[orr + 8][oc],  t[orr + 9][oc]);
    u1.y = pack2(t[orr + 10][oc], t[orr + 11][oc]);
    u1.z = pack2(t[orr + 12][oc], t[orr + 13][oc]);
    u1.w = pack2(t[orr + 14][oc], t[orr + 15][oc]);
    ushort* d = dst + (size_t)(c0 + oc) * Rd + r0 + orr;
    *(uint4*)&d[0] = u0;
    *(uint4*)&d[8] = u1;
}

__global__ __launch_bounds__(256) void transpose_bf_kernel(
    const float* __restrict__ src, ushort* __restrict__ dst, int R, int C)
{
    tile_transpose_body(src, C, dst, R, blockIdx.y * 64, blockIdx.x * 64);
}

// Wq/Wk/Wv [H, D, dh] -> WpT bf16 [1536][512]; row = p*512 + h*64 + e, col = d.
__global__ __launch_bounds__(256) void qkv_pack_kernel(
    const float* __restrict__ Wq, const float* __restrict__ Wk,
    const float* __restrict__ Wv, ushort* __restrict__ WpT)
{
    int z = blockIdx.z;
    int p = z >> 3, h = z & 7;
    const float* src = ((p == 0) ? Wq : (p == 1) ? Wk : Wv) + (size_t)h * D_MODEL * D_HEAD;
    ushort* dst = WpT + (size_t)(p * D_MODEL + h * D_HEAD) * D_MODEL;
    tile_transpose_body(src, D_HEAD, dst, D_MODEL, blockIdx.y * 64, 0);
}

__global__ __launch_bounds__(256) void pack_bias_kernel(
    const float* __restrict__ bq, const float* __restrict__ bk,
    const float* __restrict__ bv, float* __restrict__ bp)
{
    int idx = blockIdx.x * 256 + threadIdx.x;
    if (idx >= 3 * D_MODEL) return;
    int p = idx / D_MODEL;
    int h = (idx % D_MODEL) / D_HEAD;
    int e = idx % D_HEAD;
    const float* bb = (p == 0) ? bq : (p == 1) ? bk : bv;
    bp[idx] = bb[h * D_HEAD + e];
}

// ---------------------------------------------------------------- bf16 MFMA GEMM
// C = A[M,K] @ BT[N,K]^T (+bias) (+relu). BM=BN=256, BK=32.
// 512 threads = 8 waves (2 wm x 4 wn), wave tile 128x64 via 4x2 mfma_32x32x16.
// LDS: 4 K-tile buffers x (A 16KB + B 16KB) = 128KB dynamic. Distance-2
// prefetch: iter kt stages kt+2, computes kt, waits vmcnt(4) (kt+1 landed,
// kt+2 in flight), raw s_barrier + sched_barrier. Rows are 64B; swizzle
// kbyte ^= (row&3)<<4 applied on BOTH source (pre-swizzle) and reads.
// OMODE: 0 = f32 out, 1 = bf16 out, 2 = QKV split (Qg/Kg natural, Vt transp).
template<int OMODE, bool RELU>
__global__ __launch_bounds__(512, 2) void gemm_bf16_kernel(
    const ushort* __restrict__ A, const ushort* __restrict__ BT,
    const float* __restrict__ bias, void* __restrict__ Cout,
    ushort* __restrict__ Qg, ushort* __restrict__ Kg, ushort* __restrict__ Vt,
    int M, int N, int K, int nbx)
{
    extern __shared__ __align__(16) char smem[];   // 4 x 32768

    const int tid = threadIdx.x;
    const int wid = tid >> 6, l = tid & 63;
    const int wm = wid >> 2, wn = wid & 3;

    // T1: bijective XCD swizzle (gridDim.x % 8 == 0 for all our launches)
    const int cpx = gridDim.x >> 3;
    const int flat = blockIdx.x;
    const int swz = (flat & 7) * cpx + (flat >> 3);
    const int bx = swz % nbx, by = swz / nbx;
    const int m0 = by * 256, n0 = bx * 256;

    const int T = K >> 5;          // K-tiles of 32

    // stage: per thread 4 x async16 (A:2, B:2); linear LDS dest, source
    // pre-swizzled so swizzled reads see logical data (rule 21).
    #define STAGE(t)                                                           \
    if ((t) < T) {                                                             \
        char* dst_ = smem + ((t) & 3) * 32768;                                 \
        const int kb0_ = (t) * 64;                                             \
        _Pragma("unroll")                                                      \
        for (int i = 0; i < 2; ++i) {                                          \
            int X = i * 8192 + tid * 16;                                       \
            int row = X >> 6;                                                  \
            int kb = (X & 63) ^ ((row & 3) << 4);                              \
            async16((const char*)A + (size_t)(m0 + row) * (K * 2) + kb0_ + kb, \
                    dst_ + X);                                                 \
            async16((const char*)BT + (size_t)(n0 + row) * (K * 2) + kb0_ + kb,\
                    dst_ + 16384 + X);                                         \
        }                                                                      \
    }

    const int fl = l & 31, fh = l >> 5;
    const int swl = (fl & 3) << 4;

    f32x16 acc[4][2] = {};

    // prologue: kt0 + kt1 in flight; wait kt0, barrier.
    STAGE(0);
    STAGE(1);
    if (T > 1) asm volatile("s_waitcnt vmcnt(4)" ::: "memory");
    else       asm volatile("s_waitcnt vmcnt(0)" ::: "memory");
    __builtin_amdgcn_s_barrier();
    __builtin_amdgcn_sched_barrier(0);

    for (int kt = 0; kt < T; ++kt) {
        STAGE(kt + 2);

        const char* bA = smem + (kt & 3) * 32768 + (wm * 128 + fl) * 64;
        const char* bB = smem + (kt & 3) * 32768 + 16384 + (wn * 64 + fl) * 64;
        #pragma unroll
        for (int ks = 0; ks < 2; ++ks) {
            const int kb = (ks * 32 + fh * 16) ^ swl;
            bf16x8 af[4], bfv[2];
            #pragma unroll
            for (int mi = 0; mi < 4; ++mi)
                af[mi] = *(const bf16x8*)(bA + mi * 2048 + kb);
            #pragma unroll
            for (int ni = 0; ni < 2; ++ni)
                bfv[ni] = *(const bf16x8*)(bB + ni * 2048 + kb);
            __builtin_amdgcn_s_setprio(1);
            #pragma unroll
            for (int mi = 0; mi < 4; ++mi)
                #pragma unroll
                for (int ni = 0; ni < 2; ++ni)
                    acc[mi][ni] = __builtin_amdgcn_mfma_f32_32x32x16_bf16(
                        af[mi], bfv[ni], acc[mi][ni], 0, 0, 0);
            __builtin_amdgcn_s_setprio(0);
        }

        // kt+1 landed; kt+2 (4 loads) stays in flight. Never drain mid-loop.
        if (kt < T - 2) asm volatile("s_waitcnt vmcnt(4)" ::: "memory");
        else            asm volatile("s_waitcnt vmcnt(0)" ::: "memory");
        __builtin_amdgcn_s_barrier();
        __builtin_amdgcn_sched_barrier(0);
    }
    #undef STAGE

    // epilogue: 32x32 C/D layout col = l&31, row = (reg&3) + 8*(reg>>2) + 4*(l>>5)
    #pragma unroll
    for (int ni = 0; ni < 2; ++ni) {
        const int c = n0 + wn * 64 + ni * 32 + fl;
        const float bvv = bias ? bias[c] : 0.f;
        #pragma unroll
        for (int mi = 0; mi < 4; ++mi) {
            const int rbase = m0 + wm * 128 + mi * 32 + (fh << 2);
            float vv[16];
            #pragma unroll
            for (int reg = 0; reg < 16; ++reg) {
                float v = acc[mi][ni][reg] + bvv;
                if (RELU) v = fmaxf(v, 0.f);
                vv[reg] = v;
            }
            if (OMODE == 0) {
                #pragma unroll
                for (int reg = 0; reg < 16; ++reg) {
                    int r = rbase + (reg & 3) + ((reg >> 2) << 3);
                    ((float*)Cout)[(size_t)r * N + c] = vv[reg];
                }
            } else if (OMODE == 1) {
                #pragma unroll
                for (int reg = 0; reg < 16; ++reg) {
                    int r = rbase + (reg & 3) + ((reg >> 2) << 3);
                    ((ushort*)Cout)[(size_t)r * N + c] = f2bf(vv[reg]);
                }
            } else {
                const int p = n0 >> 9;            // uniform per block (BN=256)
                const int h = (c >> 6) & 7, e = c & 63;
                #pragma unroll
                for (int q = 0; q < 4; ++q) {
                    int r0 = rbase + (q << 3);    // rows r0..r0+3 (same b)
                    int b = r0 >> 9, t0 = r0 & 511;
                    size_t bh = (size_t)(b * 8 + h);
                    if (p == 2) {
                        uint2 pk;
                        pk.x = pack2(vv[q * 4 + 0], vv[q * 4 + 1]);
                        pk.y = pack2(vv[q * 4 + 2], vv[q * 4 + 3]);
                        *(uint2*)&Vt[bh * 32768 + (size_t)e * 512 + t0] = pk;
                    } else {
                        ushort* dst = (p == 0 ? Qg : Kg) + bh * 32768 +
                                      (size_t)t0 * 64 + e;
                        dst[0]   = f2bf(vv[q * 4 + 0]);
                        dst[64]  = f2bf(vv[q * 4 + 1]);
                        dst[128] = f2bf(vv[q * 4 + 2]);
                        dst[192] = f2bf(vv[q * 4 + 3]);
                    }
                }
            }
        }
    }
}

// ---------------------------------------------------------------- MFMA attention
// (unchanged from round 3/4 — passing)
__global__ __launch_bounds__(256) void attn_kernel(
    const ushort* __restrict__ Qg,   // [bh][t][e]
    const ushort* __restrict__ Kg,   // [bh][t][e]
    const ushort* __restrict__ Vt,   // [bh][e][t]
    ushort* __restrict__ O)          // [b*512+t][h*64+e]
{
    __shared__ __align__(16) char QP[8192];       // Q tile, then P strips
    __shared__ __align__(16) char KB[2][8192];
    __shared__ __align__(16) char VB[2][8192];

    const int bh = blockIdx.x, qb = blockIdx.y;
    const int tid = threadIdx.x;
    const int w = tid >> 6, l = tid & 63;

    const ushort* Qb = Qg + (size_t)bh * 32768;
    const ushort* Kb = Kg + (size_t)bh * 32768;
    const ushort* Vb = Vt + (size_t)bh * 32768;

    #pragma unroll
    for (int i = 0; i < 2; ++i) {
        int Xi = i * 4096 + tid * 16;
        int row = Xi >> 7;
        int sw = SWZ(Xi) & 127;
        async16((const char*)(Qb + (size_t)(qb * 64 + row) * 64) + sw, QP + Xi);
    }
    #define STAGEKV(kt, bb)                                                     \
        { _Pragma("unroll")                                                     \
          for (int i = 0; i < 2; ++i) {                                         \
              int Xi = i * 4096 + tid * 16;                                     \
              int row = Xi >> 7;                                                \
              int sw = SWZ(Xi) & 127;                                           \
              async16((const char*)(Kb + (size_t)((kt) * 64 + row) * 64) + sw,  \
                      KB[bb] + Xi);                                             \
              async16((const char*)(Vb + (size_t)row * 512 + (kt) * 64) + sw,   \
                      VB[bb] + Xi);                                             \
          } }
    STAGEKV(0, 0);
    __syncthreads();

    bf16x8 qf[2];
    {
        int qrow = w * 16 + (l & 15);
        #pragma unroll
        for (int ks = 0; ks < 2; ++ks) {
            int X = qrow * 128 + ks * 64 + (l >> 4) * 16;
            qf[ks] = *(const bf16x8*)(QP + SWZ(X));
        }
    }

    float mrow = -INFINITY, lrow = 0.f;
    f32x4 oacc[4] = {};

    for (int kt = 0; kt <= qb; ++kt) {
        int cur = kt & 1;
        if (kt < qb) STAGEKV(kt + 1, cur ^ 1);

        f32x4 sacc[4] = {};
        #pragma unroll
        for (int ks = 0; ks < 2; ++ks) {
            #pragma unroll
            for (int mi = 0; mi < 4; ++mi) {
                int X = (mi * 16 + (l & 15)) * 128 + ks * 64 + (l >> 4) * 16;
                bf16x8 kf = *(const bf16x8*)(KB[cur] + SWZ(X));
                sacc[mi] = __builtin_amdgcn_mfma_f32_16x16x32_bf16(
                    kf, qf[ks], sacc[mi], 0, 0, 0);
            }
        }

        float sv[16];
        float tmax = -INFINITY;
        const int qrow_t = w * 16 + (l & 15);
        #pragma unroll
        for (int mi = 0; mi < 4; ++mi)
            #pragma unroll
            for (int r = 0; r < 4; ++r) {
                float s = sacc[mi][r] * 0.125f;
                if (kt == qb) {
                    int key_l = mi * 16 + (l >> 4) * 4 + r;
                    if (key_l > qrow_t) s = -INFINITY;
                }
                sv[mi * 4 + r] = s;
                tmax = fmaxf(tmax, s);
            }
        tmax = fmaxf(tmax, __shfl_xor(tmax, 16));
        tmax = fmaxf(tmax, __shfl_xor(tmax, 32));
        float mnew = fmaxf(mrow, tmax);
        float corr = __expf(mrow - mnew);
        mrow = mnew;
        float psum = 0.f;
        #pragma unroll
        for (int i = 0; i < 16; ++i) { sv[i] = __expf(sv[i] - mnew); psum += sv[i]; }
        psum += __shfl_xor(psum, 16);
        psum += __shfl_xor(psum, 32);
        lrow = lrow * corr + psum;

        #pragma unroll
        for (int mi = 0; mi < 4; ++mi) {
            uint2 pk;
            pk.x = pack2(sv[mi * 4 + 0], sv[mi * 4 + 1]);
            pk.y = pack2(sv[mi * 4 + 2], sv[mi * 4 + 3]);
            int X = qrow_t * 128 + (mi * 16 + (l >> 4) * 4) * 2;
            *(uint2*)(QP + SWZ(X)) = pk;
        }

        #pragma unroll
        for (int r = 0; r < 4; ++r) {
            float cr = __shfl(corr, (l & 48) | ((l >> 4) * 4 + r));
            #pragma unroll
            for (int n = 0; n < 4; ++n) oacc[n][r] *= cr;
        }

        #pragma unroll
        for (int ks = 0; ks < 2; ++ks) {
            int Xa = qrow_t * 128 + ks * 64 + (l >> 4) * 16;
            bf16x8 pa = *(const bf16x8*)(QP + SWZ(Xa));
            #pragma unroll
            for (int n = 0; n < 4; ++n) {
                int Xb = (n * 16 + (l & 15)) * 128 + ks * 64 + (l >> 4) * 16;
                bf16x8 vb = *(const bf16x8*)(VB[cur] + SWZ(Xb));
                oacc[n] = __builtin_amdgcn_mfma_f32_16x16x32_bf16(
                    pa, vb, oacc[n], 0, 0, 0);
            }
        }
        __syncthreads();
    }

    float linv = 1.0f / lrow;
    const int b_ = bh >> 3, h_ = bh & 7;
    #pragma unroll
    for (int r = 0; r < 4; ++r) {
        float li = __shfl(linv, (l & 48) | ((l >> 4) * 4 + r));
        int trow = qb * 64 + w * 16 + (l >> 4) * 4 + r;
        size_t obase = ((size_t)b_ * 512 + trow) * 512 + h_ * 64 + (l & 15);
        #pragma unroll
        for (int n = 0; n < 4; ++n)
            O[obase + n * 16] = f2bf(oacc[n][r] * li);
    }
}

// ---------------------------------------------------------------- LN + residual
template<bool WBF>
__global__ __launch_bounds__(256) void ln_res_kernel(
    const float* __restrict__ v, const float* __restrict__ res,
    const float* __restrict__ g, const float* __restrict__ bb,
    float* __restrict__ out, ushort* __restrict__ out_bf)
{
    int row  = blockIdx.x * 4 + (threadIdx.x >> 6);
    int lane = threadIdx.x & 63;
    const float4* vp = (const float4*)(v + (size_t)row * D_MODEL);
    float4 a = vp[lane];
    float4 c = vp[lane + 64];
    float sum = a.x + a.y + a.z + a.w + c.x + c.y + c.z + c.w;
    float sq  = a.x*a.x + a.y*a.y + a.z*a.z + a.w*a.w
              + c.x*c.x + c.y*c.y + c.z*c.z + c.w*c.w;
    #pragma unroll
    for (int o = 1; o < 64; o <<= 1) {
        sum += __shfl_xor(sum, o);
        sq  += __shfl_xor(sq, o);
    }
    float mu   = sum * (1.f / 512.f);
    float var  = sq * (1.f / 512.f) - mu * mu;
    float rstd = rsqrtf(var + 1e-5f);

    const float4* rp = (const float4*)(res + (size_t)row * D_MODEL);
    const float4* gp = (const float4*)g;
    const float4* bp = (const float4*)bb;
    float4 r0 = rp[lane], r1 = rp[lane + 64];
    float4 g0 = gp[lane], g1 = gp[lane + 64];
    float4 b0 = bp[lane], b1 = bp[lane + 64];
    float4 o0, o1;
    o0.x = r0.x + (a.x - mu) * rstd * g0.x + b0.x;
    o0.y = r0.y + (a.y - mu) * rstd * g0.y + b0.y;
    o0.z = r0.z + (a.z - mu) * rstd * g0.z + b0.z;
    o0.w = r0.w + (a.w - mu) * rstd * g0.w + b0.w;
    o1.x = r1.x + (c.x - mu) * rstd * g1.x + b1.x;
    o1.y = r1.y + (c.y - mu) * rstd * g1.y + b1.y;
    o1.z = r1.z + (c.z - mu) * rstd * g1.z + b1.z;
    o1.w = r1.w + (c.w - mu) * rstd * g1.w + b1.w;
    float4* op = (float4*)(out + (size_t)row * D_MODEL);
    op[lane] = o0;
    op[lane + 64] = o1;
    if (WBF) {
        uint2 p0, p1;
        p0.x = pack2(o0.x, o0.y); p0.y = pack2(o0.z, o0.w);
        p1.x = pack2(o1.x, o1.y); p1.y = pack2(o1.z, o1.w);
        *(uint2*)&out_bf[(size_t)row * D_MODEL + lane * 4] = p0;
        *(uint2*)&out_bf[(size_t)row * D_MODEL + 256 + lane * 4] = p1;
    }
}

// ---------------------------------------------------------------- launch
extern "C" void kernel_launch(void* const* d_in, const int* in_sizes, int n_in,
                              void* d_out, int out_size, void* d_ws, size_t ws_size,
                              hipStream_t stream)
{
    const float* x     = (const float*)d_in[0];
    const float* Wq    = (const float*)d_in[1];
    const float* bq    = (const float*)d_in[2];
    const float* Wk    = (const float*)d_in[3];
    const float* bk    = (const float*)d_in[4];
    const float* Wv    = (const float*)d_in[5];
    const float* bv    = (const float*)d_in[6];
    const float* Wo    = (const float*)d_in[7];
    const float* bo    = (const float*)d_in[8];
    const float* ln1_g = (const float*)d_in[9];
    const float* ln1_b = (const float*)d_in[10];
    const float* W1    = (const float*)d_in[11];
    const float* b1    = (const float*)d_in[12];
    const float* W2    = (const float*)d_in[13];
    const float* b2    = (const float*)d_in[14];
    const float* ln2_g = (const float*)d_in[15];
    const float* ln2_b = (const float*)d_in[16];

    float* ws = (float*)d_ws;
    ushort* Qg      = (ushort*)(ws);               // 8,388,608 us
    ushort* Kg      = (ushort*)(ws + 4194304);     // 8,388,608 us
    ushort* Vt      = (ushort*)(ws + 8388608);     // 8,388,608 us
    ushort* O_bf    = (ushort*)(ws + 12582912);    // 8,388,608 us
    float*  attnb   = ws + 16777216;               // 8,388,608 f32 (ff2 aliases)
    float*  out1    = ws + 25165824;               // 8,388,608 f32
    ushort* out1_bf = (ushort*)(ws + 33554432);    // 8,388,608 us
    ushort* x_bf    = (ushort*)(ws + 37748736);    // 8,388,608 us
    ushort* WpT     = (ushort*)(ws + 41943040);    // 786,432 us
    ushort* WoT     = (ushort*)(ws + 42336256);    // 262,144 us
    ushort* W1T     = (ushort*)(ws + 42467328);    // 1,048,576 us
    ushort* W2T     = (ushort*)(ws + 42991616);    // 1,048,576 us
    float*  bp      = ws + 43515904;               // 1,536 f32
    ushort* ff1_bf  = (ushort*)ws;                 // 33,554,432 us (alias)
    float*  ff2     = attnb;

    // allow 128KB dynamic LDS (idempotent; ignore errors)
    (void)hipFuncSetAttribute(
        reinterpret_cast<const void*>(&gemm_bf16_kernel<2, false>),
        hipFuncAttributeMaxDynamicSharedMemorySize, 131072);
    (void)hipFuncSetAttribute(
        reinterpret_cast<const void*>(&gemm_bf16_kernel<0, false>),
        hipFuncAttributeMaxDynamicSharedMemorySize, 131072);
    (void)hipFuncSetAttribute(
        reinterpret_cast<const void*>(&gemm_bf16_kernel<1, true>),
        hipFuncAttributeMaxDynamicSharedMemorySize, 131072);

    conv_bf_kernel<<<dim3(4096), 256, 0, stream>>>(x, x_bf, NROWS * D_MODEL / 8);
    qkv_pack_kernel<<<dim3(1, 8, 24), 256, 0, stream>>>(Wq, Wk, Wv, WpT);
    transpose_bf_kernel<<<dim3(8, 8), 256, 0, stream>>>(Wo, WoT, 512, 512);
    transpose_bf_kernel<<<dim3(32, 8), 256, 0, stream>>>(W1, W1T, 512, 2048);
    transpose_bf_kernel<<<dim3(8, 32), 256, 0, stream>>>(W2, W2T, 2048, 512);
    pack_bias_kernel<<<dim3(6), 256, 0, stream>>>(bq, bk, bv, bp);

    // QKV: x @ Wp + bp -> Qg/Kg natural, Vt transposed. grid 64*6=384 (%8==0)
    gemm_bf16_kernel<2, false><<<dim3(384), 512, 131072, stream>>>(
        x_bf, WpT, bp, nullptr, Qg, Kg, Vt, NROWS, 1536, 512, 6);

    // attention -> O_bf
    attn_kernel<<<dim3(256, 8), 256, 0, stream>>>(Qg, Kg, Vt, O_bf);

    // attn = O @ Wo + bo  (fp32 out). grid 64*2=128
    gemm_bf16_kernel<0, false><<<dim3(128), 512, 131072, stream>>>(
        O_bf, WoT, bo, attnb, nullptr, nullptr, nullptr, NROWS, 512, 512, 2);

    // out1 = x + LN(attn); + bf16 copy
    ln_res_kernel<true><<<dim3(NROWS / 4), 256, 0, stream>>>(
        attnb, x, ln1_g, ln1_b, out1, out1_bf);

    // ff1 = relu(out1 @ W1 + b1) -> bf16. grid 64*8=512
    gemm_bf16_kernel<1, true><<<dim3(512), 512, 131072, stream>>>(
        out1_bf, W1T, b1, ff1_bf, nullptr, nullptr, nullptr, NROWS, 2048, 512, 8);

    // ff2 = ff1 @ W2 + b2  (fp32 out). grid 64*2=128, T=64
    gemm_bf16_kernel<0, false><<<dim3(128), 512, 131072, stream>>>(
        ff1_bf, W2T, b2, ff2, nullptr, nullptr, nullptr, NROWS, 512, 2048, 2);

    // out = out1 + LN(ff2)
    ln_res_kernel<false><<<dim3(NROWS / 4), 256, 0, stream>>>(
        ff2, out1, ln2_g, ln2_b, (float*)d_out, nullptr);
}

// Round 6
// 234.877 us; speedup vs baseline: 1.1839x; 1.1839x over previous
//
#include <hip/hip_runtime.h>
#include <hip/hip_bf16.h>

// Decoder block, round 6: GEMM ported to the m201-style 8-phase schedule.
// BM=256, BK=64, 8 waves (2m x 4n), wave tile 128x(NF*16), mfma_16x16x32.
// Quarter-granular staging ring (2-tile parity), counted vmcnt(4)/vmcnt(2),
// 2 barriers/K-tile, setprio around MFMA clusters, depth-8 XOR swizzle.
// NF=4 (BN=256) for QKV/ff1; NF=2 (BN=128) for Wo/ff2 (full-chip grids).
// Attention / LN / prep unchanged (passing since round 3).

#define D_MODEL 512
#define N_HEADS 8
#define D_HEAD 64
#define D_FF 2048
#define NROWS 16384   // B*T

typedef __bf16 bf16x8 __attribute__((ext_vector_type(8)));
typedef float f32x4 __attribute__((ext_vector_type(4)));

// XOR swizzle within a 128B-row tile: involution, bits 4-6 ^= row&7.
#define SWZ(x) ((x) ^ ((((x) >> 7) & 7) << 4))

static __device__ __forceinline__ ushort f2bf(float f) {
    union { float f; unsigned u; } v; v.f = f;
    unsigned r = v.u + 0x7fffu + ((v.u >> 16) & 1u);   // RNE
    return (ushort)(r >> 16);
}
static __device__ __forceinline__ unsigned pack2(float lo, float hi) {
    return (unsigned)f2bf(lo) | ((unsigned)f2bf(hi) << 16);
}
static __device__ __forceinline__ void async16(const void* g, void* l) {
    __builtin_amdgcn_global_load_lds(
        (const __attribute__((address_space(1))) void*)g,
        (__attribute__((address_space(3))) void*)l, 16, 0, 0);
}

// ---------------------------------------------------------------- fp32 -> bf16
__global__ __launch_bounds__(256) void conv_bf_kernel(
    const float* __restrict__ src, ushort* __restrict__ dst, int n8)
{
    int i = blockIdx.x * 256 + threadIdx.x;
    if (i >= n8) return;
    const float4* s = (const float4*)src;
    float4 a = s[i * 2], b = s[i * 2 + 1];
    uint4 o;
    o.x = pack2(a.x, a.y); o.y = pack2(a.z, a.w);
    o.z = pack2(b.x, b.y); o.w = pack2(b.z, b.w);
    ((uint4*)dst)[i] = o;
}

// ---------------------------------------------------------------- transpose fp32[R][C] -> bf16[C][R]
static __device__ __forceinline__ void tile_transpose_body(
    const float* __restrict__ src, int srcldc, ushort* __restrict__ dst, int Rd,
    int r0, int c0)
{
    __shared__ float t[64][65];
    int tid = threadIdx.x;
    int lr = tid >> 4, lc4 = (tid & 15) * 4;
    #pragma unroll
    for (int i = 0; i < 4; ++i) {
        float4 v = *(const float4*)&src[(size_t)(r0 + lr + i * 16) * srcldc + c0 + lc4];
        t[lr + i * 16][lc4 + 0] = v.x;
        t[lr + i * 16][lc4 + 1] = v.y;
        t[lr + i * 16][lc4 + 2] = v.z;
        t[lr + i * 16][lc4 + 3] = v.w;
    }
    __syncthreads();
    int oc = tid >> 2, orr = (tid & 3) * 16;
    uint4 u0, u1;
    u0.x = pack2(t[orr + 0][oc],  t[orr + 1][oc]);
    u0.y = pack2(t[orr + 2][oc],  t[orr + 3][oc]);
    u0.z = pack2(t[orr + 4][oc],  t[orr + 5][oc]);
    u0.w = pack2(t[orr + 6][oc],  t[orr + 7][oc]);
    u1.x = pack2(t[orr + 8][oc],  t[orr + 9][oc]);
    u1.y = pack2(t[orr + 10][oc], t[orr + 11][oc]);
    u1.z = pack2(t[orr + 12][oc], t[orr + 13][oc]);
    u1.w = pack2(t[orr + 14][oc], t[orr + 15][oc]);
    ushort* d = dst + (size_t)(c0 + oc) * Rd + r0 + orr;
    *(uint4*)&d[0] = u0;
    *(uint4*)&d[8] = u1;
}

__global__ __launch_bounds__(256) void transpose_bf_kernel(
    const float* __restrict__ src, ushort* __restrict__ dst, int R, int C)
{
    tile_transpose_body(src, C, dst, R, blockIdx.y * 64, blockIdx.x * 64);
}

// Wq/Wk/Wv [H, D, dh] -> WpT bf16 [1536][512]; row = p*512 + h*64 + e, col = d.
__global__ __launch_bounds__(256) void qkv_pack_kernel(
    const float* __restrict__ Wq, const float* __restrict__ Wk,
    const float* __restrict__ Wv, ushort* __restrict__ WpT)
{
    int z = blockIdx.z;
    int p = z >> 3, h = z & 7;
    const float* src = ((p == 0) ? Wq : (p == 1) ? Wk : Wv) + (size_t)h * D_MODEL * D_HEAD;
    ushort* dst = WpT + (size_t)(p * D_MODEL + h * D_HEAD) * D_MODEL;
    tile_transpose_body(src, D_HEAD, dst, D_MODEL, blockIdx.y * 64, 0);
}

__global__ __launch_bounds__(256) void pack_bias_kernel(
    const float* __restrict__ bq, const float* __restrict__ bk,
    const float* __restrict__ bv, float* __restrict__ bp)
{
    int idx = blockIdx.x * 256 + threadIdx.x;
    if (idx >= 3 * D_MODEL) return;
    int p = idx / D_MODEL;
    int h = (idx % D_MODEL) / D_HEAD;
    int e = idx % D_HEAD;
    const float* bb = (p == 0) ? bq : (p == 1) ? bk : bv;
    bp[idx] = bb[h * D_HEAD + e];
}

// ---------------------------------------------------------------- 8-phase GEMM
// C = A[M,K] @ BT[N,K]^T (+bias) (+relu). BM=256, BN=NF*64, BK=64.
// 512 thr = 8 waves (wm 0..1, wn 0..3); wave tile 128 x NF*16.
// LDS: parity ring of 8KB quarters: per parity, A quarters 0..3 (rows m0+q*64)
// then B quarters 0..NF-1. Stage sets: P0 = {B*} (NF4) / {A0,A2,B0,B1} (NF2);
// P1 = {A0,A2,A1,A3} / {A1,A3} -- last 2 issued are always A{1,3}(t+1).
// Waits: end-S0 vmcnt(4), end-S1 vmcnt(2) (A{1,3}(t) oldest at guard point).
// OMODE: 0 = f32 out, 1 = bf16 out, 2 = QKV split (Qg/Kg natural, Vt transp).
template<int NF, int OMODE, bool RELU>
__global__ __launch_bounds__(512, 1) void gemm8p_kernel(
    const ushort* __restrict__ A, const ushort* __restrict__ BT,
    const float* __restrict__ bias, void* __restrict__ Cout,
    ushort* __restrict__ Qg, ushort* __restrict__ Kg, ushort* __restrict__ Vt,
    int M, int N, int K, int nbx)
{
    extern __shared__ __align__(16) char smem[];
    constexpr int ABYTES = 32768;                 // 4 A-quarters
    constexpr int PAR = ABYTES + NF * 8192;      // parity stride

    const int tid = threadIdx.x;
    const int wid = tid >> 6, l = tid & 63;
    const int wm = wid >> 2, wn = wid & 3;

    // T1: bijective XCD swizzle (gridDim.x % 8 == 0 for all launches)
    const int cpx = gridDim.x >> 3;
    const int flat = blockIdx.x;
    const int swz = (flat & 7) * cpx + (flat >> 3);
    const int bx = swz % nbx, by = swz / nbx;
    const int m0 = by * 256, n0 = bx * (NF * 64);

    const char* Ac = (const char*)A;
    const char* Bc = (const char*)BT;
    const size_t K2 = (size_t)K * 2;
    const int T = K >> 6;

    // staging geometry: 1 quarter (8KB) per macro call, 1 load/thread.
    const int srow = tid >> 3;
    const int ssw  = ((tid & 7) ^ (srow & 7)) << 4;

    #define STG_A(t, q_) async16(Ac + (size_t)(m0 + (q_) * 64 + srow) * K2 +  \
                                     (size_t)(t) * 128 + ssw,                 \
                                 smem + (((t) & 1) ? PAR : 0) + (q_) * 8192 + \
                                     tid * 16)
    #define STG_B(t, q_) async16(Bc + (size_t)(n0 + (q_) * 64 + srow) * K2 +  \
                                     (size_t)(t) * 128 + ssw,                 \
                                 smem + (((t) & 1) ? PAR : 0) + ABYTES +      \
                                     (q_) * 8192 + tid * 16)
    #define P0SET(t) do { if constexpr (NF == 4) {                            \
                              STG_B(t,0); STG_B(t,1); STG_B(t,2); STG_B(t,3);}\
                          else { STG_A(t,0); STG_A(t,2);                      \
                                 STG_B(t,0); STG_B(t,1); } } while (0)
    #define P1SET(t) do { if constexpr (NF == 4) {                            \
                              STG_A(t,0); STG_A(t,2); STG_A(t,1); STG_A(t,3);}\
                          else { STG_A(t,1); STG_A(t,3); } } while (0)

    const int fr = l & 15, fq = l >> 4;
    const int rsw = (fr & 7) << 4;

    f32x4 acc[8][NF] = {};

    // prologue: tile 0 fully staged; A{1,3} may stay in flight.
    P0SET(0);
    P1SET(0);
    asm volatile("s_waitcnt vmcnt(2)" ::: "memory");
    __builtin_amdgcn_s_barrier();
    __builtin_amdgcn_sched_barrier(0);

    for (int t = 0; t < T; ++t) {
        const char* par = smem + ((t & 1) ? PAR : 0);
        #pragma unroll
        for (int S = 0; S < 2; ++S) {
            // A fragments for this super-phase (quarter wm*2+S)
            const char* bufA = par + (wm * 2 + S) * 8192;
            bf16x8 af[4][2];
            #pragma unroll
            for (int mi = 0; mi < 4; ++mi)
                #pragma unroll
                for (int ks = 0; ks < 2; ++ks)
                    af[mi][ks] = *(const bf16x8*)(bufA + (mi * 16 + fr) * 128 +
                        ((ks * 64 + fq * 16) ^ rsw));
            // B fragments, sub-cluster 0
            bf16x8 bf0[NF / 2][2], bf1[NF / 2][2];
            #pragma unroll
            for (int nj = 0; nj < NF / 2; ++nj)
                #pragma unroll
                for (int ks = 0; ks < 2; ++ks) {
                    int grow = wn * (NF * 16) + nj * 16 + fr;
                    bf0[nj][ks] = *(const bf16x8*)(par + ABYTES +
                        (grow >> 6) * 8192 + (grow & 63) * 128 +
                        ((ks * 64 + fq * 16) ^ rsw));
                }
            // stage next tile's set while reads/MFMA run
            if (t + 1 < T) { if (S == 0) P0SET(t + 1); else P1SET(t + 1); }
            // B fragments, sub-cluster 1
            #pragma unroll
            for (int nj = 0; nj < NF / 2; ++nj)
                #pragma unroll
                for (int ks = 0; ks < 2; ++ks) {
                    int grow = wn * (NF * 16) + (NF / 2) * 16 + nj * 16 + fr;
                    bf1[nj][ks] = *(const bf16x8*)(par + ABYTES +
                        (grow >> 6) * 8192 + (grow & 63) * 128 +
                        ((ks * 64 + fq * 16) ^ rsw));
                }

            __builtin_amdgcn_s_setprio(1);
            #pragma unroll
            for (int mi = 0; mi < 4; ++mi)
                #pragma unroll
                for (int nj = 0; nj < NF / 2; ++nj) {
                    f32x4 a = acc[S * 4 + mi][nj];
                    a = __builtin_amdgcn_mfma_f32_16x16x32_bf16(af[mi][0], bf0[nj][0], a, 0, 0, 0);
                    a = __builtin_amdgcn_mfma_f32_16x16x32_bf16(af[mi][1], bf0[nj][1], a, 0, 0, 0);
                    acc[S * 4 + mi][nj] = a;
                }
            __builtin_amdgcn_s_setprio(0);
            __builtin_amdgcn_s_setprio(1);
            #pragma unroll
            for (int mi = 0; mi < 4; ++mi)
                #pragma unroll
                for (int nj = 0; nj < NF / 2; ++nj) {
                    f32x4 a = acc[S * 4 + mi][NF / 2 + nj];
                    a = __builtin_amdgcn_mfma_f32_16x16x32_bf16(af[mi][0], bf1[nj][0], a, 0, 0, 0);
                    a = __builtin_amdgcn_mfma_f32_16x16x32_bf16(af[mi][1], bf1[nj][1], a, 0, 0, 0);
                    acc[S * 4 + mi][NF / 2 + nj] = a;
                }
            __builtin_amdgcn_s_setprio(0);

            // counted waits -- never 0 mid-loop (ledger in header comment)
            if (S == 0) {
                if (t + 1 < T) asm volatile("s_waitcnt vmcnt(4)" ::: "memory");
                else           asm volatile("s_waitcnt vmcnt(0)" ::: "memory");
            } else {
                if (t + 1 < T) asm volatile("s_waitcnt vmcnt(2)" ::: "memory");
                else           asm volatile("s_waitcnt vmcnt(0)" ::: "memory");
            }
            __builtin_amdgcn_s_barrier();
            __builtin_amdgcn_sched_barrier(0);
        }
    }
    #undef STG_A
    #undef STG_B
    #undef P0SET
    #undef P1SET

    // epilogue: 16x16 C/D layout col = l&15, row = (l>>4)*4 + reg
    #pragma unroll
    for (int mi = 0; mi < 8; ++mi) {
        const int r0 = m0 + wm * 128 + mi * 16 + fq * 4;
        #pragma unroll
        for (int nf = 0; nf < NF; ++nf) {
            const int c = n0 + wn * (NF * 16) + nf * 16 + fr;
            const float bvv = bias ? bias[c] : 0.f;
            float vv[4];
            #pragma unroll
            for (int reg = 0; reg < 4; ++reg) {
                float v = acc[mi][nf][reg] + bvv;
                if (RELU) v = fmaxf(v, 0.f);
                vv[reg] = v;
            }
            if (OMODE == 0) {
                #pragma unroll
                for (int reg = 0; reg < 4; ++reg)
                    ((float*)Cout)[(size_t)(r0 + reg) * N + c] = vv[reg];
            } else if (OMODE == 1) {
                #pragma unroll
                for (int reg = 0; reg < 4; ++reg)
                    ((ushort*)Cout)[(size_t)(r0 + reg) * N + c] = f2bf(vv[reg]);
            } else {
                const int p = n0 >> 9;             // uniform (n0 % 512 in {0,256})
                const int h = (c >> 6) & 7, e = c & 63;
                const int b = r0 >> 9, t0 = r0 & 511;
                const size_t bh = (size_t)(b * 8 + h);
                if (p == 2) {
                    uint2 pk;
                    pk.x = pack2(vv[0], vv[1]);
                    pk.y = pack2(vv[2], vv[3]);
                    *(uint2*)&Vt[bh * 32768 + (size_t)e * 512 + t0] = pk;
                } else {
                    ushort* dst = (p == 0 ? Qg : Kg) + bh * 32768 +
                                  (size_t)t0 * 64 + e;
                    dst[0]   = f2bf(vv[0]);
                    dst[64]  = f2bf(vv[1]);
                    dst[128] = f2bf(vv[2]);
                    dst[192] = f2bf(vv[3]);
                }
            }
        }
    }
}

// ---------------------------------------------------------------- MFMA attention
// (unchanged from round 3 -- passing)
__global__ __launch_bounds__(256) void attn_kernel(
    const ushort* __restrict__ Qg,   // [bh][t][e]
    const ushort* __restrict__ Kg,   // [bh][t][e]
    const ushort* __restrict__ Vt,   // [bh][e][t]
    ushort* __restrict__ O)          // [b*512+t][h*64+e]
{
    __shared__ __align__(16) char QP[8192];       // Q tile, then P strips
    __shared__ __align__(16) char KB[2][8192];
    __shared__ __align__(16) char VB[2][8192];

    const int bh = blockIdx.x, qb = blockIdx.y;
    const int tid = threadIdx.x;
    const int w = tid >> 6, l = tid & 63;

    const ushort* Qb = Qg + (size_t)bh * 32768;
    const ushort* Kb = Kg + (size_t)bh * 32768;
    const ushort* Vb = Vt + (size_t)bh * 32768;

    #pragma unroll
    for (int i = 0; i < 2; ++i) {
        int Xi = i * 4096 + tid * 16;
        int row = Xi >> 7;
        int sw = SWZ(Xi) & 127;
        async16((const char*)(Qb + (size_t)(qb * 64 + row) * 64) + sw, QP + Xi);
    }
    #define STAGEKV(kt, bb)                                                     \
        { _Pragma("unroll")                                                     \
          for (int i = 0; i < 2; ++i) {                                         \
              int Xi = i * 4096 + tid * 16;                                     \
              int row = Xi >> 7;                                                \
              int sw = SWZ(Xi) & 127;                                           \
              async16((const char*)(Kb + (size_t)((kt) * 64 + row) * 64) + sw,  \
                      KB[bb] + Xi);                                             \
              async16((const char*)(Vb + (size_t)row * 512 + (kt) * 64) + sw,   \
                      VB[bb] + Xi);                                             \
          } }
    STAGEKV(0, 0);
    __syncthreads();

    bf16x8 qf[2];
    {
        int qrow = w * 16 + (l & 15);
        #pragma unroll
        for (int ks = 0; ks < 2; ++ks) {
            int X = qrow * 128 + ks * 64 + (l >> 4) * 16;
            qf[ks] = *(const bf16x8*)(QP + SWZ(X));
        }
    }

    float mrow = -INFINITY, lrow = 0.f;
    f32x4 oacc[4] = {};

    for (int kt = 0; kt <= qb; ++kt) {
        int cur = kt & 1;
        if (kt < qb) STAGEKV(kt + 1, cur ^ 1);

        f32x4 sacc[4] = {};
        #pragma unroll
        for (int ks = 0; ks < 2; ++ks) {
            #pragma unroll
            for (int mi = 0; mi < 4; ++mi) {
                int X = (mi * 16 + (l & 15)) * 128 + ks * 64 + (l >> 4) * 16;
                bf16x8 kf = *(const bf16x8*)(KB[cur] + SWZ(X));
                sacc[mi] = __builtin_amdgcn_mfma_f32_16x16x32_bf16(
                    kf, qf[ks], sacc[mi], 0, 0, 0);
            }
        }

        float sv[16];
        float tmax = -INFINITY;
        const int qrow_t = w * 16 + (l & 15);
        #pragma unroll
        for (int mi = 0; mi < 4; ++mi)
            #pragma unroll
            for (int r = 0; r < 4; ++r) {
                float s = sacc[mi][r] * 0.125f;
                if (kt == qb) {
                    int key_l = mi * 16 + (l >> 4) * 4 + r;
                    if (key_l > qrow_t) s = -INFINITY;
                }
                sv[mi * 4 + r] = s;
                tmax = fmaxf(tmax, s);
            }
        tmax = fmaxf(tmax, __shfl_xor(tmax, 16));
        tmax = fmaxf(tmax, __shfl_xor(tmax, 32));
        float mnew = fmaxf(mrow, tmax);
        float corr = __expf(mrow - mnew);
        mrow = mnew;
        float psum = 0.f;
        #pragma unroll
        for (int i = 0; i < 16; ++i) { sv[i] = __expf(sv[i] - mnew); psum += sv[i]; }
        psum += __shfl_xor(psum, 16);
        psum += __shfl_xor(psum, 32);
        lrow = lrow * corr + psum;

        #pragma unroll
        for (int mi = 0; mi < 4; ++mi) {
            uint2 pk;
            pk.x = pack2(sv[mi * 4 + 0], sv[mi * 4 + 1]);
            pk.y = pack2(sv[mi * 4 + 2], sv[mi * 4 + 3]);
            int X = qrow_t * 128 + (mi * 16 + (l >> 4) * 4) * 2;
            *(uint2*)(QP + SWZ(X)) = pk;
        }

        #pragma unroll
        for (int r = 0; r < 4; ++r) {
            float cr = __shfl(corr, (l & 48) | ((l >> 4) * 4 + r));
            #pragma unroll
            for (int n = 0; n < 4; ++n) oacc[n][r] *= cr;
        }

        #pragma unroll
        for (int ks = 0; ks < 2; ++ks) {
            int Xa = qrow_t * 128 + ks * 64 + (l >> 4) * 16;
            bf16x8 pa = *(const bf16x8*)(QP + SWZ(Xa));
            #pragma unroll
            for (int n = 0; n < 4; ++n) {
                int Xb = (n * 16 + (l & 15)) * 128 + ks * 64 + (l >> 4) * 16;
                bf16x8 vb = *(const bf16x8*)(VB[cur] + SWZ(Xb));
                oacc[n] = __builtin_amdgcn_mfma_f32_16x16x32_bf16(
                    pa, vb, oacc[n], 0, 0, 0);
            }
        }
        __syncthreads();
    }

    float linv = 1.0f / lrow;
    const int b_ = bh >> 3, h_ = bh & 7;
    #pragma unroll
    for (int r = 0; r < 4; ++r) {
        float li = __shfl(linv, (l & 48) | ((l >> 4) * 4 + r));
        int trow = qb * 64 + w * 16 + (l >> 4) * 4 + r;
        size_t obase = ((size_t)b_ * 512 + trow) * 512 + h_ * 64 + (l & 15);
        #pragma unroll
        for (int n = 0; n < 4; ++n)
            O[obase + n * 16] = f2bf(oacc[n][r] * li);
    }
}

// ---------------------------------------------------------------- LN + residual
template<bool WBF>
__global__ __launch_bounds__(256) void ln_res_kernel(
    const float* __restrict__ v, const float* __restrict__ res,
    const float* __restrict__ g, const float* __restrict__ bb,
    float* __restrict__ out, ushort* __restrict__ out_bf)
{
    int row  = blockIdx.x * 4 + (threadIdx.x >> 6);
    int lane = threadIdx.x & 63;
    const float4* vp = (const float4*)(v + (size_t)row * D_MODEL);
    float4 a = vp[lane];
    float4 c = vp[lane + 64];
    float sum = a.x + a.y + a.z + a.w + c.x + c.y + c.z + c.w;
    float sq  = a.x*a.x + a.y*a.y + a.z*a.z + a.w*a.w
              + c.x*c.x + c.y*c.y + c.z*c.z + c.w*c.w;
    #pragma unroll
    for (int o = 1; o < 64; o <<= 1) {
        sum += __shfl_xor(sum, o);
        sq  += __shfl_xor(sq, o);
    }
    float mu   = sum * (1.f / 512.f);
    float var  = sq * (1.f / 512.f) - mu * mu;
    float rstd = rsqrtf(var + 1e-5f);

    const float4* rp = (const float4*)(res + (size_t)row * D_MODEL);
    const float4* gp = (const float4*)g;
    const float4* bp = (const float4*)bb;
    float4 r0 = rp[lane], r1 = rp[lane + 64];
    float4 g0 = gp[lane], g1 = gp[lane + 64];
    float4 b0 = bp[lane], b1 = bp[lane + 64];
    float4 o0, o1;
    o0.x = r0.x + (a.x - mu) * rstd * g0.x + b0.x;
    o0.y = r0.y + (a.y - mu) * rstd * g0.y + b0.y;
    o0.z = r0.z + (a.z - mu) * rstd * g0.z + b0.z;
    o0.w = r0.w + (a.w - mu) * rstd * g0.w + b0.w;
    o1.x = r1.x + (c.x - mu) * rstd * g1.x + b1.x;
    o1.y = r1.y + (c.y - mu) * rstd * g1.y + b1.y;
    o1.z = r1.z + (c.z - mu) * rstd * g1.z + b1.z;
    o1.w = r1.w + (c.w - mu) * rstd * g1.w + b1.w;
    float4* op = (float4*)(out + (size_t)row * D_MODEL);
    op[lane] = o0;
    op[lane + 64] = o1;
    if (WBF) {
        uint2 p0, p1;
        p0.x = pack2(o0.x, o0.y); p0.y = pack2(o0.z, o0.w);
        p1.x = pack2(o1.x, o1.y); p1.y = pack2(o1.z, o1.w);
        *(uint2*)&out_bf[(size_t)row * D_MODEL + lane * 4] = p0;
        *(uint2*)&out_bf[(size_t)row * D_MODEL + 256 + lane * 4] = p1;
    }
}

// ---------------------------------------------------------------- launch
extern "C" void kernel_launch(void* const* d_in, const int* in_sizes, int n_in,
                              void* d_out, int out_size, void* d_ws, size_t ws_size,
                              hipStream_t stream)
{
    const float* x     = (const float*)d_in[0];
    const float* Wq    = (const float*)d_in[1];
    const float* bq    = (const float*)d_in[2];
    const float* Wk    = (const float*)d_in[3];
    const float* bk    = (const float*)d_in[4];
    const float* Wv    = (const float*)d_in[5];
    const float* bv    = (const float*)d_in[6];
    const float* Wo    = (const float*)d_in[7];
    const float* bo    = (const float*)d_in[8];
    const float* ln1_g = (const float*)d_in[9];
    const float* ln1_b = (const float*)d_in[10];
    const float* W1    = (const float*)d_in[11];
    const float* b1    = (const float*)d_in[12];
    const float* W2    = (const float*)d_in[13];
    const float* b2    = (const float*)d_in[14];
    const float* ln2_g = (const float*)d_in[15];
    const float* ln2_b = (const float*)d_in[16];

    float* ws = (float*)d_ws;
    ushort* Qg      = (ushort*)(ws);               // 8,388,608 us
    ushort* Kg      = (ushort*)(ws + 4194304);     // 8,388,608 us
    ushort* Vt      = (ushort*)(ws + 8388608);     // 8,388,608 us
    ushort* O_bf    = (ushort*)(ws + 12582912);    // 8,388,608 us
    float*  attnb   = ws + 16777216;               // 8,388,608 f32 (ff2 aliases)
    float*  out1    = ws + 25165824;               // 8,388,608 f32
    ushort* out1_bf = (ushort*)(ws + 33554432);    // 8,388,608 us
    ushort* x_bf    = (ushort*)(ws + 37748736);    // 8,388,608 us
    ushort* WpT     = (ushort*)(ws + 41943040);    // 786,432 us
    ushort* WoT     = (ushort*)(ws + 42336256);    // 262,144 us
    ushort* W1T     = (ushort*)(ws + 42467328);    // 1,048,576 us
    ushort* W2T     = (ushort*)(ws + 42991616);    // 1,048,576 us
    float*  bp      = ws + 43515904;               // 1,536 f32
    ushort* ff1_bf  = (ushort*)ws;                 // 33,554,432 us (alias)
    float*  ff2     = attnb;

    // allow big dynamic LDS (idempotent; ignore errors)
    (void)hipFuncSetAttribute(
        reinterpret_cast<const void*>(&gemm8p_kernel<4, 2, false>),
        hipFuncAttributeMaxDynamicSharedMemorySize, 131072);
    (void)hipFuncSetAttribute(
        reinterpret_cast<const void*>(&gemm8p_kernel<4, 1, true>),
        hipFuncAttributeMaxDynamicSharedMemorySize, 131072);
    (void)hipFuncSetAttribute(
        reinterpret_cast<const void*>(&gemm8p_kernel<2, 0, false>),
        hipFuncAttributeMaxDynamicSharedMemorySize, 98304);

    conv_bf_kernel<<<dim3(4096), 256, 0, stream>>>(x, x_bf, NROWS * D_MODEL / 8);
    qkv_pack_kernel<<<dim3(1, 8, 24), 256, 0, stream>>>(Wq, Wk, Wv, WpT);
    transpose_bf_kernel<<<dim3(8, 8), 256, 0, stream>>>(Wo, WoT, 512, 512);
    transpose_bf_kernel<<<dim3(32, 8), 256, 0, stream>>>(W1, W1T, 512, 2048);
    transpose_bf_kernel<<<dim3(8, 32), 256, 0, stream>>>(W2, W2T, 2048, 512);
    pack_bias_kernel<<<dim3(6), 256, 0, stream>>>(bq, bk, bv, bp);

    // QKV: x @ Wp + bp -> Qg/Kg natural, Vt transposed. grid 64*6=384
    gemm8p_kernel<4, 2, false><<<dim3(384), 512, 131072, stream>>>(
        x_bf, WpT, bp, nullptr, Qg, Kg, Vt, NROWS, 1536, 512, 6);

    // attention -> O_bf
    attn_kernel<<<dim3(256, 8), 256, 0, stream>>>(Qg, Kg, Vt, O_bf);

    // attn = O @ Wo + bo  (fp32 out). NF=2, grid 64*4=256 (full chip)
    gemm8p_kernel<2, 0, false><<<dim3(256), 512, 98304, stream>>>(
        O_bf, WoT, bo, attnb, nullptr, nullptr, nullptr, NROWS, 512, 512, 4);

    // out1 = x + LN(attn); + bf16 copy
    ln_res_kernel<true><<<dim3(NROWS / 4), 256, 0, stream>>>(
        attnb, x, ln1_g, ln1_b, out1, out1_bf);

    // ff1 = relu(out1 @ W1 + b1) -> bf16. grid 64*8=512
    gemm8p_kernel<4, 1, true><<<dim3(512), 512, 131072, stream>>>(
        out1_bf, W1T, b1, ff1_bf, nullptr, nullptr, nullptr, NROWS, 2048, 512, 8);

    // ff2 = ff1 @ W2 + b2  (fp32 out). NF=2, grid 64*4=256, T=32
    gemm8p_kernel<2, 0, false><<<dim3(256), 512, 98304, stream>>>(
        ff1_bf, W2T, b2, ff2, nullptr, nullptr, nullptr, NROWS, 512, 2048, 4);

    // out = out1 + LN(ff2)
    ln_res_kernel<false><<<dim3(NROWS / 4), 256, 0, stream>>>(
        ff2, out1, ln2_g, ln2_b, (float*)d_out, nullptr);
}